// Round 1
// baseline (210.673 us; speedup 1.0000x reference)
//
#include <hip/hip_runtime.h>
#include <hip/hip_fp16.h>
#include <cmath>

#define N_NODES 50000
#define N_EDGES 800000
#define D 64
#define N_REL 8

#define NODES_PER_BLK 32
#define TN 16                       // nodes per block in tables_kernel
#define CPAD 16                     // cnt stride in ints: 64B line per counter
#define MAXDEG 64                   // ELL row pad; P(deg>64 | Poisson(16)) ~ 1e-20
#define NSEG 8                      // dst segments == XCD count
#define SEG_DIV 6250                // 50000 / 8
#define VPT 8                       // edges per thread in scatter (batched MLP)

typedef int v4i __attribute__((ext_vector_type(4)));

// float -> bf16 bits, round-to-nearest-even
static __device__ __forceinline__ unsigned f2bf(float f) {
    unsigned u = __float_as_uint(f);
    return (u + 0x7FFFu + ((u >> 16) & 1u)) >> 16;
}
#define BFLO(u) __uint_as_float((u) << 16)
#define BFHI(u) __uint_as_float((u) & 0xFFFF0000u)

// ---------------------------------------------------------------------------
// K0: w[r*128 + j] = sum_k W_r[r][j][k]  + zero the padded cnt array
// ---------------------------------------------------------------------------
__global__ void wprep_kernel(const float* __restrict__ W_r, float* __restrict__ w,
                             int* __restrict__ cnt) {
    int t = blockIdx.x * blockDim.x + threadIdx.x;
    if (t < N_REL * 2 * D) {
        const float* p = W_r + (size_t)t * D;
        float s = 0.0f;
#pragma unroll
        for (int k = 0; k < D; ++k) s += p[k];
        w[t] = s;
    }
    for (int i = t; i < N_NODES * CPAD; i += gridDim.x * blockDim.x)
        cnt[i] = 0;
}

// ---------------------------------------------------------------------------
// K1: logit tables (tall-skinny GEMM) + xb side-product (packed bf16 x).
// ---------------------------------------------------------------------------
__global__ __launch_bounds__(256) void tables_kernel(
    const float* __restrict__ x, const float* __restrict__ w,
    float* __restrict__ Dn, float* __restrict__ Sr,
    unsigned short* __restrict__ xb)
{
    __shared__ float xs[TN][68];
    __shared__ float ws[16][68];

    int tid = threadIdx.x;
    int n0  = blockIdx.x * TN;

    for (int i = tid; i < 16 * 64; i += 256)
        ws[i >> 6][i & 63] = w[i];
    for (int i = tid; i < TN * 64; i += 256) {
        int n = n0 + (i >> 6);
        xs[i >> 6][i & 63] = (n < N_NODES) ? x[(size_t)n * D + (i & 63)] : 0.f;
    }
    __syncthreads();

    for (int i = tid; i < TN * 64; i += 256) {
        int n = n0 + (i >> 6);
        if (n < N_NODES) xb[(size_t)n0 * D + i] = (unsigned short)f2bf(xs[i >> 6][i & 63]);
    }

    int q = tid & 15, nl = tid >> 4;
    float acc = 0.f;
#pragma unroll
    for (int k = 0; k < 64; k += 4) {
        float4 a = *(const float4*)&xs[nl][k];
        float4 b = *(const float4*)&ws[q][k];
        acc += a.x * b.x + a.y * b.y + a.z * b.z + a.w * b.w;
    }
    int n = n0 + nl;
    if (n < N_NODES) {
        int r = q >> 1;
        if ((q & 1) == 0) Dn[n * 8 + r] = acc;
        else              Sr[n * 8 + r] = acc;
    }
}

// ---------------------------------------------------------------------------
// K2: XCD-partitioned ELL scatter, VPT=8 edges/thread, phase-batched loads.
//
// Previous version (1 edge/thread) was latency-chain bound: 100K waves each
// paying ~4 dependent memory round-trips -> 55us with VALUBusy 11%, BW 23%.
// Now each thread runs 8 independent chains: all dst loads issue together
// (int4x2, nontemporal), then src/rel for surviving edges, then all Dn/Sr
// gathers, then 8 independent atomics+stores. 12.5K waves, 8-way MLP.
//
// Edge record packed to 4B: src fits in 16 bits (50000 < 65536), gate in
// fp16 (relerr 2^-11 << bf16-x's 2^-8). Per-segment epack slice 1.6MB ->
// resident in the owning XCD's 4MB L2 so stores can write-combine; the
// streaming dst/src/rel loads are nontemporal so they don't evict it.
// ---------------------------------------------------------------------------
__global__ __launch_bounds__(256) void scatter_kernel(
    const int* __restrict__ src, const int* __restrict__ dst,
    const int* __restrict__ rel,
    int* __restrict__ cnt,
    const float* __restrict__ Dn, const float* __restrict__ Sr,
    unsigned int* __restrict__ epack) {
    int seg   = blockIdx.x & (NSEG - 1);
    int chunk = blockIdx.x >> 3;
    int e0 = (chunk * 256 + threadIdx.x) * VPT;
    if (e0 >= N_EDGES) return;          // N_EDGES % VPT == 0: groups never split

    // phase 1: all dst loads (coalesced 32B/lane, streaming)
    v4i da = __builtin_nontemporal_load((const v4i*)(dst + e0));
    v4i db = __builtin_nontemporal_load((const v4i*)(dst + e0 + 4));
    int d[VPT] = {da[0], da[1], da[2], da[3], db[0], db[1], db[2], db[3]};

    bool act[VPT];
#pragma unroll
    for (int i = 0; i < VPT; ++i)
        act[i] = ((unsigned)d[i] / SEG_DIV) == (unsigned)seg;   // magic-mul div

    // phase 2: src/rel for survivors (independent, issue back-to-back)
    int s[VPT], r[VPT];
#pragma unroll
    for (int i = 0; i < VPT; ++i) {
        s[i] = 0; r[i] = 0;
        if (act[i]) {
            s[i] = __builtin_nontemporal_load(src + e0 + i);
            r[i] = __builtin_nontemporal_load(rel + e0 + i);
        }
    }

    // phase 3: table gathers (16 independent 4B loads, L2-resident tables)
    float dn[VPT], sr[VPT];
#pragma unroll
    for (int i = 0; i < VPT; ++i) {
        dn[i] = 0.f; sr[i] = 0.f;
        if (act[i]) {
            dn[i] = Dn[d[i] * 8 + r[i]];
            sr[i] = Sr[s[i] * 8 + r[i]];
        }
    }

    // phase 4: independent atomics + dependent stores
#pragma unroll
    for (int i = 0; i < VPT; ++i) {
        if (act[i]) {
            float gate = 1.0f / (1.0f + __expf(-(dn[i] + sr[i])));
            unsigned pv = ((unsigned)__half_as_ushort(__float2half_rn(gate)) << 16)
                        | (unsigned)s[i];
            int rank = atomicAdd(&cnt[d[i] * CPAD], 1);
            if (rank < MAXDEG)
                epack[(size_t)d[i] * MAXDEG + rank] = pv;
        }
    }
}

// ---------------------------------------------------------------------------
// K3: aggregation over ELL rows, bf16 gathers, packed bf16 output.
// epack entries are 4B: (fp16 gate << 16) | src.
// ---------------------------------------------------------------------------
__global__ __launch_bounds__(256) void agg_kernel(
    const unsigned short* __restrict__ xb,
    const int*   __restrict__ cnt,
    const unsigned int* __restrict__ epack,
    unsigned int* __restrict__ aggb)   // (N_NODES, 32) packed bf16 pairs
{
    int n    = (blockIdx.x * blockDim.x + threadIdx.x) >> 6;
    int lane = threadIdx.x & 63;
    if (n >= N_NODES) return;

    int sub = lane >> 4;      // edge slot 0..3
    int q   = lane & 15;      // dims 4q..4q+3
    int deg = cnt[n * CPAD];
    int m   = (deg < MAXDEG) ? deg : MAXDEG;
    int beg = n * MAXDEG;
    int end = beg + m;

    float ax = 0.f, ay = 0.f, az = 0.f, aw = 0.f;

    for (int base = beg; base < end; base += 8) {
        int e0 = base + sub;
        int e1 = base + 4 + sub;
        float g0 = 0.f, g1 = 0.f;
        int   s0 = 0,   s1 = 0;
        if (e0 < end) {
            unsigned v = epack[e0];
            g0 = __half2float(__ushort_as_half((unsigned short)(v >> 16)));
            s0 = (int)(v & 0xFFFFu);
        }
        if (e1 < end) {
            unsigned v = epack[e1];
            g1 = __half2float(__ushort_as_half((unsigned short)(v >> 16)));
            s1 = (int)(v & 0xFFFFu);
        }
        uint2 u0 = {0u, 0u}, u1 = {0u, 0u};
        if (e0 < end) u0 = *(const uint2*)&xb[(size_t)s0 * D + 4 * q];
        if (e1 < end) u1 = *(const uint2*)&xb[(size_t)s1 * D + 4 * q];
        ax += g0 * BFLO(u0.x) + g1 * BFLO(u1.x);
        ay += g0 * BFHI(u0.x) + g1 * BFHI(u1.x);
        az += g0 * BFLO(u0.y) + g1 * BFLO(u1.y);
        aw += g0 * BFHI(u0.y) + g1 * BFHI(u1.y);
    }

#pragma unroll
    for (int off = 16; off <= 32; off <<= 1) {
        ax += __shfl_xor(ax, off, 64);
        ay += __shfl_xor(ay, off, 64);
        az += __shfl_xor(az, off, 64);
        aw += __shfl_xor(aw, off, 64);
    }

    if (sub == 0) {
        float inv = 1.0f / fmaxf((float)deg, 1.0f);   // normalize by TRUE degree
        uint2 pr;
        pr.x = f2bf(ax * inv) | (f2bf(ay * inv) << 16);
        pr.y = f2bf(az * inv) | (f2bf(aw * inv) << 16);
        *(uint2*)&aggb[(size_t)n * 32 + 2 * q] = pr;
    }
}

// ---------------------------------------------------------------------------
// K4: out = leaky_relu([x, agg] @ W_lin^T + b), all LDS operands bf16-packed.
// ---------------------------------------------------------------------------
__global__ __launch_bounds__(256, 6) void lin_kernel(
    const unsigned int* __restrict__ xbu,   // packed x, 32 uints/node
    const unsigned int* __restrict__ aggb,  // packed agg, 32 uints/node
    const float* __restrict__ W_lin,
    const float* __restrict__ b_lin,
    float* __restrict__ out)
{
    __shared__ unsigned int W2[64][66];
    __shared__ unsigned int c2[NODES_PER_BLK][66];
    __shared__ float b_lds[64];

    int tid = threadIdx.x;
    int n0  = blockIdx.x * NODES_PER_BLK;

    for (int i = tid; i < 64 * 64; i += 256) {
        int j = i >> 6, kp = i & 63;
        float2 wv = *(const float2*)&W_lin[j * 128 + kp * 2];
        W2[j][kp] = f2bf(wv.x) | (f2bf(wv.y) << 16);
    }
    if (tid < 64) b_lds[tid] = b_lin[tid];

    for (int i = tid; i < NODES_PER_BLK * 32; i += 256) {
        int nl = i >> 5, kp = i & 31;
        int n  = n0 + nl;
        unsigned vx = 0u, va = 0u;
        if (n < N_NODES) {
            vx = xbu[(size_t)n * 32 + kp];
            va = aggb[(size_t)n * 32 + kp];
        }
        c2[nl][kp]      = vx;
        c2[nl][32 + kp] = va;
    }
    __syncthreads();

    int tx = tid & 15, ty = tid >> 4;
    float acc[2][4];
#pragma unroll
    for (int i = 0; i < 2; ++i)
#pragma unroll
        for (int jj = 0; jj < 4; ++jj) acc[i][jj] = b_lds[tx + 16 * jj];

#pragma unroll 2
    for (int kp = 0; kp < 64; kp += 2) {      // 2 pairs = 4 dims per iter
        uint2 cu[2], wu[4];
        cu[0] = *(const uint2*)&c2[ty][kp];
        cu[1] = *(const uint2*)&c2[ty + 16][kp];
#pragma unroll
        for (int jj = 0; jj < 4; ++jj)
            wu[jj] = *(const uint2*)&W2[tx + 16 * jj][kp];
#pragma unroll
        for (int i = 0; i < 2; ++i) {
            float cx = BFLO(cu[i].x), cy = BFHI(cu[i].x);
            float cz = BFLO(cu[i].y), cw = BFHI(cu[i].y);
#pragma unroll
            for (int jj = 0; jj < 4; ++jj) {
                acc[i][jj] += cx * BFLO(wu[jj].x) + cy * BFHI(wu[jj].x)
                            + cz * BFLO(wu[jj].y) + cw * BFHI(wu[jj].y);
            }
        }
    }

#pragma unroll
    for (int i = 0; i < 2; ++i) {
        int n = n0 + ty + 16 * i;
        if (n < N_NODES) {
#pragma unroll
            for (int jj = 0; jj < 4; ++jj) {
                float v = acc[i][jj];
                out[(size_t)n * D + tx + 16 * jj] = (v > 0.f) ? v : 0.01f * v;
            }
        }
    }
}

// ---------------------------------------------------------------------------
extern "C" void kernel_launch(void* const* d_in, const int* in_sizes, int n_in,
                              void* d_out, int out_size, void* d_ws, size_t ws_size,
                              hipStream_t stream) {
    const float* x     = (const float*)d_in[0];
    const int*   src   = (const int*)  d_in[1];
    const int*   dst   = (const int*)  d_in[2];
    const int*   rel   = (const int*)  d_in[3];
    const float* W_r   = (const float*)d_in[4];
    const float* W_lin = (const float*)d_in[5];
    const float* b_lin = (const float*)d_in[6];
    float* out = (float*)d_out;

    char* p = (char*)d_ws;
    float*  w       = (float*)p;                p += 4096;
    float*  Dn      = (float*)p;                p += (size_t)N_NODES * 8 * 4;       // 1.6 MB
    float*  Sr      = (float*)p;                p += (size_t)N_NODES * 8 * 4;       // 1.6 MB
    int*    cnt     = (int*)p;                  p += (size_t)N_NODES * CPAD * 4;    // 3.2 MB
    unsigned int* epack = (unsigned int*)p;     p += (size_t)N_NODES * MAXDEG * 4;  // 12.8 MB
    unsigned short* xb = (unsigned short*)p;    p += (size_t)N_NODES * D * 2;       // 6.4 MB
    unsigned int* aggb = (unsigned int*)p;      p += (size_t)N_NODES * 32 * 4;      // 6.4 MB

    wprep_kernel<<<512, 256, 0, stream>>>(W_r, w, cnt);
    tables_kernel<<<(N_NODES + TN - 1) / TN, 256, 0, stream>>>(x, w, Dn, Sr, xb);
    scatter_kernel<<<NSEG * ((N_EDGES + 256 * VPT - 1) / (256 * VPT)), 256, 0, stream>>>(
        src, dst, rel, cnt, Dn, Sr, epack);
    agg_kernel<<<(N_NODES * 64 + 255) / 256, 256, 0, stream>>>(xb, cnt, epack, aggb);
    lin_kernel<<<(N_NODES + NODES_PER_BLK - 1) / NODES_PER_BLK, 256, 0, stream>>>(
        (const unsigned int*)xb, aggb, W_lin, b_lin, out);
}

// Round 2
// 186.367 us; speedup vs baseline: 1.1304x; 1.1304x over previous
//
#include <hip/hip_runtime.h>
#include <hip/hip_fp16.h>
#include <cmath>

#define N_NODES 50000
#define N_EDGES 800000
#define D 64
#define N_REL 8

#define NODES_PER_BLK 32
#define TN 16                       // nodes per block in tables_kernel
#define CPAD 16                     // cnt stride in ints: 64B line per counter
#define MAXDEG 64                   // ELL row pad; P(deg>64 | Poisson(16)) ~ 1e-20
#define NSEG 8                      // dst segments == XCD count
#define SEG_DIV 6250                // 50000 / 8

// float -> bf16 bits, round-to-nearest-even
static __device__ __forceinline__ unsigned f2bf(float f) {
    unsigned u = __float_as_uint(f);
    return (u + 0x7FFFu + ((u >> 16) & 1u)) >> 16;
}
#define BFLO(u) __uint_as_float((u) << 16)
#define BFHI(u) __uint_as_float((u) & 0xFFFF0000u)

// ---------------------------------------------------------------------------
// K0: w[r*128 + j] = sum_k W_r[r][j][k]  + zero the padded cnt array
// ---------------------------------------------------------------------------
__global__ void wprep_kernel(const float* __restrict__ W_r, float* __restrict__ w,
                             int* __restrict__ cnt) {
    int t = blockIdx.x * blockDim.x + threadIdx.x;
    if (t < N_REL * 2 * D) {
        const float* p = W_r + (size_t)t * D;
        float s = 0.0f;
#pragma unroll
        for (int k = 0; k < D; ++k) s += p[k];
        w[t] = s;
    }
    for (int i = t; i < N_NODES * CPAD; i += gridDim.x * blockDim.x)
        cnt[i] = 0;
}

// ---------------------------------------------------------------------------
// K1: logit tables (tall-skinny GEMM) + xb side-product (packed bf16 x).
// ---------------------------------------------------------------------------
__global__ __launch_bounds__(256) void tables_kernel(
    const float* __restrict__ x, const float* __restrict__ w,
    float* __restrict__ Dn, float* __restrict__ Sr,
    unsigned short* __restrict__ xb)
{
    __shared__ float xs[TN][68];
    __shared__ float ws[16][68];

    int tid = threadIdx.x;
    int n0  = blockIdx.x * TN;

    for (int i = tid; i < 16 * 64; i += 256)
        ws[i >> 6][i & 63] = w[i];
    for (int i = tid; i < TN * 64; i += 256) {
        int n = n0 + (i >> 6);
        xs[i >> 6][i & 63] = (n < N_NODES) ? x[(size_t)n * D + (i & 63)] : 0.f;
    }
    __syncthreads();

    for (int i = tid; i < TN * 64; i += 256) {
        int n = n0 + (i >> 6);
        if (n < N_NODES) xb[(size_t)n0 * D + i] = (unsigned short)f2bf(xs[i >> 6][i & 63]);
    }

    int q = tid & 15, nl = tid >> 4;
    float acc = 0.f;
#pragma unroll
    for (int k = 0; k < 64; k += 4) {
        float4 a = *(const float4*)&xs[nl][k];
        float4 b = *(const float4*)&ws[q][k];
        acc += a.x * b.x + a.y * b.y + a.z * b.z + a.w * b.w;
    }
    int n = n0 + nl;
    if (n < N_NODES) {
        int r = q >> 1;
        if ((q & 1) == 0) Dn[n * 8 + r] = acc;
        else              Sr[n * 8 + r] = acc;
    }
}

// ---------------------------------------------------------------------------
// K2: XCD-partitioned ELL scatter, 1 edge/thread.
//
// R1 post-mortem: VPT=8 batching regressed (55->68us) -- filter divergence
// made the unrolled phases issue mostly-masked work. Back to 1 edge/thread.
// Two latency-chain cuts vs R0:
//  (1) dst/src/rel are loaded UNCONDITIONALLY, back-to-back, and pinned
//      before the segment filter (asm keep-alive). All three round-trips
//      overlap instead of dst -> (wait) -> src/rel. Extra src/rel traffic
//      (full read per pass) is served by the 256MB L3 -- the whole edge
//      list is 9.6MB, L3-resident after the first pass.
//  (2) the rank atomic depends only on d, so it issues BEFORE the Dn/Sr
//      gathers; atomic latency overlaps gather latency.
// Edge record stays packed to 4B (R1's one confirmed win: WRITE 47->36MB).
// ---------------------------------------------------------------------------
__global__ __launch_bounds__(256) void scatter_kernel(
    const int* __restrict__ src, const int* __restrict__ dst,
    const int* __restrict__ rel,
    int* __restrict__ cnt,
    const float* __restrict__ Dn, const float* __restrict__ Sr,
    unsigned int* __restrict__ epack) {
    int seg   = blockIdx.x & (NSEG - 1);
    int chunk = blockIdx.x >> 3;
    int e = chunk * 256 + threadIdx.x;
    if (e >= N_EDGES) return;

    // issue all three coalesced loads before any dependent use
    int d = dst[e];
    int s = src[e];
    int r = rel[e];
    // pin: forbid sinking src/rel loads into the survivor branch
    asm volatile("" :: "v"(d), "v"(s), "v"(r));

    if ((unsigned)d / SEG_DIV != (unsigned)seg) return;   // magic-mul div

    // rank is independent of gate: issue the atomic first, overlap gathers
    int rank = atomicAdd(&cnt[d * CPAD], 1);

    float logit = Dn[d * 8 + r] + Sr[s * 8 + r];
    float gate = 1.0f / (1.0f + __expf(-logit));
    if (rank < MAXDEG) {
        unsigned pv = ((unsigned)__half_as_ushort(__float2half_rn(gate)) << 16)
                    | (unsigned)s;
        epack[(size_t)d * MAXDEG + rank] = pv;
    }
}

// ---------------------------------------------------------------------------
// K3: aggregation over ELL rows, bf16 gathers, packed bf16 output.
// epack entries are 4B: (fp16 gate << 16) | src.
// ---------------------------------------------------------------------------
__global__ __launch_bounds__(256) void agg_kernel(
    const unsigned short* __restrict__ xb,
    const int*   __restrict__ cnt,
    const unsigned int* __restrict__ epack,
    unsigned int* __restrict__ aggb)   // (N_NODES, 32) packed bf16 pairs
{
    int n    = (blockIdx.x * blockDim.x + threadIdx.x) >> 6;
    int lane = threadIdx.x & 63;
    if (n >= N_NODES) return;

    int sub = lane >> 4;      // edge slot 0..3
    int q   = lane & 15;      // dims 4q..4q+3
    int deg = cnt[n * CPAD];
    int m   = (deg < MAXDEG) ? deg : MAXDEG;
    int beg = n * MAXDEG;
    int end = beg + m;

    float ax = 0.f, ay = 0.f, az = 0.f, aw = 0.f;

    for (int base = beg; base < end; base += 8) {
        int e0 = base + sub;
        int e1 = base + 4 + sub;
        float g0 = 0.f, g1 = 0.f;
        int   s0 = 0,   s1 = 0;
        if (e0 < end) {
            unsigned v = epack[e0];
            g0 = __half2float(__ushort_as_half((unsigned short)(v >> 16)));
            s0 = (int)(v & 0xFFFFu);
        }
        if (e1 < end) {
            unsigned v = epack[e1];
            g1 = __half2float(__ushort_as_half((unsigned short)(v >> 16)));
            s1 = (int)(v & 0xFFFFu);
        }
        uint2 u0 = {0u, 0u}, u1 = {0u, 0u};
        if (e0 < end) u0 = *(const uint2*)&xb[(size_t)s0 * D + 4 * q];
        if (e1 < end) u1 = *(const uint2*)&xb[(size_t)s1 * D + 4 * q];
        ax += g0 * BFLO(u0.x) + g1 * BFLO(u1.x);
        ay += g0 * BFHI(u0.x) + g1 * BFHI(u1.x);
        az += g0 * BFLO(u0.y) + g1 * BFLO(u1.y);
        aw += g0 * BFHI(u0.y) + g1 * BFHI(u1.y);
    }

#pragma unroll
    for (int off = 16; off <= 32; off <<= 1) {
        ax += __shfl_xor(ax, off, 64);
        ay += __shfl_xor(ay, off, 64);
        az += __shfl_xor(az, off, 64);
        aw += __shfl_xor(aw, off, 64);
    }

    if (sub == 0) {
        float inv = 1.0f / fmaxf((float)deg, 1.0f);   // normalize by TRUE degree
        uint2 pr;
        pr.x = f2bf(ax * inv) | (f2bf(ay * inv) << 16);
        pr.y = f2bf(az * inv) | (f2bf(aw * inv) << 16);
        *(uint2*)&aggb[(size_t)n * 32 + 2 * q] = pr;
    }
}

// ---------------------------------------------------------------------------
// K4: out = leaky_relu([x, agg] @ W_lin^T + b), all LDS operands bf16-packed.
// ---------------------------------------------------------------------------
__global__ __launch_bounds__(256, 6) void lin_kernel(
    const unsigned int* __restrict__ xbu,   // packed x, 32 uints/node
    const unsigned int* __restrict__ aggb,  // packed agg, 32 uints/node
    const float* __restrict__ W_lin,
    const float* __restrict__ b_lin,
    float* __restrict__ out)
{
    __shared__ unsigned int W2[64][66];
    __shared__ unsigned int c2[NODES_PER_BLK][66];
    __shared__ float b_lds[64];

    int tid = threadIdx.x;
    int n0  = blockIdx.x * NODES_PER_BLK;

    for (int i = tid; i < 64 * 64; i += 256) {
        int j = i >> 6, kp = i & 63;
        float2 wv = *(const float2*)&W_lin[j * 128 + kp * 2];
        W2[j][kp] = f2bf(wv.x) | (f2bf(wv.y) << 16);
    }
    if (tid < 64) b_lds[tid] = b_lin[tid];

    for (int i = tid; i < NODES_PER_BLK * 32; i += 256) {
        int nl = i >> 5, kp = i & 31;
        int n  = n0 + nl;
        unsigned vx = 0u, va = 0u;
        if (n < N_NODES) {
            vx = xbu[(size_t)n * 32 + kp];
            va = aggb[(size_t)n * 32 + kp];
        }
        c2[nl][kp]      = vx;
        c2[nl][32 + kp] = va;
    }
    __syncthreads();

    int tx = tid & 15, ty = tid >> 4;
    float acc[2][4];
#pragma unroll
    for (int i = 0; i < 2; ++i)
#pragma unroll
        for (int jj = 0; jj < 4; ++jj) acc[i][jj] = b_lds[tx + 16 * jj];

#pragma unroll 2
    for (int kp = 0; kp < 64; kp += 2) {      // 2 pairs = 4 dims per iter
        uint2 cu[2], wu[4];
        cu[0] = *(const uint2*)&c2[ty][kp];
        cu[1] = *(const uint2*)&c2[ty + 16][kp];
#pragma unroll
        for (int jj = 0; jj < 4; ++jj)
            wu[jj] = *(const uint2*)&W2[tx + 16 * jj][kp];
#pragma unroll
        for (int i = 0; i < 2; ++i) {
            float cx = BFLO(cu[i].x), cy = BFHI(cu[i].x);
            float cz = BFLO(cu[i].y), cw = BFHI(cu[i].y);
#pragma unroll
            for (int jj = 0; jj < 4; ++jj) {
                acc[i][jj] += cx * BFLO(wu[jj].x) + cy * BFHI(wu[jj].x)
                            + cz * BFLO(wu[jj].y) + cw * BFHI(wu[jj].y);
            }
        }
    }

#pragma unroll
    for (int i = 0; i < 2; ++i) {
        int n = n0 + ty + 16 * i;
        if (n < N_NODES) {
#pragma unroll
            for (int jj = 0; jj < 4; ++jj) {
                float v = acc[i][jj];
                out[(size_t)n * D + tx + 16 * jj] = (v > 0.f) ? v : 0.01f * v;
            }
        }
    }
}

// ---------------------------------------------------------------------------
extern "C" void kernel_launch(void* const* d_in, const int* in_sizes, int n_in,
                              void* d_out, int out_size, void* d_ws, size_t ws_size,
                              hipStream_t stream) {
    const float* x     = (const float*)d_in[0];
    const int*   src   = (const int*)  d_in[1];
    const int*   dst   = (const int*)  d_in[2];
    const int*   rel   = (const int*)  d_in[3];
    const float* W_r   = (const float*)d_in[4];
    const float* W_lin = (const float*)d_in[5];
    const float* b_lin = (const float*)d_in[6];
    float* out = (float*)d_out;

    char* p = (char*)d_ws;
    float*  w       = (float*)p;                p += 4096;
    float*  Dn      = (float*)p;                p += (size_t)N_NODES * 8 * 4;       // 1.6 MB
    float*  Sr      = (float*)p;                p += (size_t)N_NODES * 8 * 4;       // 1.6 MB
    int*    cnt     = (int*)p;                  p += (size_t)N_NODES * CPAD * 4;    // 3.2 MB
    unsigned int* epack = (unsigned int*)p;     p += (size_t)N_NODES * MAXDEG * 4;  // 12.8 MB
    unsigned short* xb = (unsigned short*)p;    p += (size_t)N_NODES * D * 2;       // 6.4 MB
    unsigned int* aggb = (unsigned int*)p;      p += (size_t)N_NODES * 32 * 4;      // 6.4 MB

    wprep_kernel<<<512, 256, 0, stream>>>(W_r, w, cnt);
    tables_kernel<<<(N_NODES + TN - 1) / TN, 256, 0, stream>>>(x, w, Dn, Sr, xb);
    scatter_kernel<<<NSEG * ((N_EDGES + 255) / 256), 256, 0, stream>>>(
        src, dst, rel, cnt, Dn, Sr, epack);
    agg_kernel<<<(N_NODES * 64 + 255) / 256, 256, 0, stream>>>(xb, cnt, epack, aggb);
    lin_kernel<<<(N_NODES + NODES_PER_BLK - 1) / NODES_PER_BLK, 256, 0, stream>>>(
        (const unsigned int*)xb, aggb, W_lin, b_lin, out);
}